// Round 11
// baseline (123.894 us; speedup 1.0000x reference)
//
#include <hip/hip_runtime.h>
#include <math.h>

#define C_IN  128
#define C_HID 64
#define C_OUT 40
#define H1DW  32                      // dwords per h1/out1 row (64 bf16)
#define H2DW  20                      // dwords per h2 row (40 bf16)

#define BKT_SH 7
#define BKT_N  (1 << BKT_SH)          // 128 nodes per bucket
#define CHUNK  1024                   // edges per hist/binA block
#define EPT    (CHUNK / 256)          // 4 edges per thread

__device__ __forceinline__ float bf2f(unsigned short u) {
    return __uint_as_float(((unsigned int)u) << 16);
}
__device__ __forceinline__ unsigned short f2bf(float f) {   // round-to-nearest-even
    unsigned int x = __float_as_uint(f);
    return (unsigned short)((x + 0x7FFFu + ((x >> 16) & 1u)) >> 16);
}

// ---------------- pass 0: per-chunk, per-bucket histogram (no global atomics) ----------------
__global__ void k_hist(const int* __restrict__ dst, int* __restrict__ hist2d, int e, int nbkt) {
    __shared__ int hist[512];
    for (int i = threadIdx.x; i < nbkt; i += 256) hist[i] = 0;
    __syncthreads();
    int base = blockIdx.x * CHUNK;
#pragma unroll
    for (int j = 0; j < EPT; ++j) {
        int i = base + j * 256 + threadIdx.x;
        if (i < e) atomicAdd(&hist[dst[i] >> BKT_SH], 1);
    }
    __syncthreads();
    int* row = hist2d + (size_t)blockIdx.x * nbkt;
    for (int i = threadIdx.x; i < nbkt; i += 256) row[i] = hist[i];
}

// ---------------- per-bucket scan over chunks (looped, carry): base2d + tot ----------------
__global__ void k_bktscan(const int* __restrict__ hist2d, int* __restrict__ base2d,
                          int* __restrict__ tot, int nchunks, int nbkt) {
    __shared__ int wtot[4];
    const int b = blockIdx.x;
    const int t = threadIdx.x;
    const int lane = t & 63, wv = t >> 6;
    int carry = 0;
    for (int c0 = 0; c0 < nchunks; c0 += 256) {
        int c = c0 + t;
        int v = (c < nchunks) ? hist2d[(size_t)c * nbkt + b] : 0;
        int inc = v;
        for (int o = 1; o < 64; o <<= 1) { int u = __shfl_up(inc, o); if (lane >= o) inc += u; }
        if (lane == 63) wtot[wv] = inc;
        __syncthreads();
        int add = carry;
        for (int k = 0; k < wv; ++k) add += wtot[k];
        if (c < nchunks) base2d[(size_t)c * nbkt + b] = add + inc - v;
        carry += wtot[0] + wtot[1] + wtot[2] + wtot[3];
        __syncthreads();
    }
    if (t == 0) tot[b] = carry;
}

// ---------------- scan over bucket totals (looped, carry) -> bstart ----------------
__global__ void k_scan_bkt(const int* __restrict__ tot, int* __restrict__ bstart, int nbkt, int e) {
    __shared__ int wtot[4];
    const int t = threadIdx.x;
    const int lane = t & 63, wv = t >> 6;
    int carry = 0;
    for (int b0 = 0; b0 < nbkt; b0 += 256) {
        int b = b0 + t;
        int v = (b < nbkt) ? tot[b] : 0;
        int inc = v;
        for (int o = 1; o < 64; o <<= 1) { int u = __shfl_up(inc, o); if (lane >= o) inc += u; }
        if (lane == 63) wtot[wv] = inc;
        __syncthreads();
        int add = carry;
        for (int k = 0; k < wv; ++k) add += wtot[k];
        if (b < nbkt) bstart[b] = add + inc - v;
        carry += wtot[0] + wtot[1] + wtot[2] + wtot[3];
        __syncthreads();
    }
    if (t == 0) bstart[nbkt] = e;
}

// ---------------- pass A: LDS multisplit by bucket (hist reused from hist2d) ----------------
__global__ void k_binA(const int* __restrict__ src, const int* __restrict__ dst,
                       const int* __restrict__ bstart, const int* __restrict__ hist2d,
                       const int* __restrict__ base2d, unsigned int* __restrict__ bpack,
                       int e, int nbkt) {
    __shared__ int hist[512];          // local cursors
    __shared__ int excl[512];
    __shared__ int gbase[512];
    __shared__ int wtot[4];
    __shared__ unsigned int stage[CHUNK];
    const int t = threadIdx.x;
    const int base = blockIdx.x * CHUNK;
    const int lane = t & 63, wv = t >> 6;

    int carry = 0;
    for (int b0 = 0; b0 < nbkt; b0 += 256) {
        int b = b0 + t;
        int v = (b < nbkt) ? hist2d[(size_t)blockIdx.x * nbkt + b] : 0;
        int inc = v;
        for (int o = 1; o < 64; o <<= 1) { int u = __shfl_up(inc, o); if (lane >= o) inc += u; }
        if (lane == 63) wtot[wv] = inc;
        __syncthreads();
        int add = carry;
        for (int k = 0; k < wv; ++k) add += wtot[k];
        if (b < nbkt) {
            excl[b]  = add + inc - v;
            hist[b]  = 0;
            gbase[b] = bstart[b] + base2d[(size_t)blockIdx.x * nbkt + b];
        }
        carry += wtot[0] + wtot[1] + wtot[2] + wtot[3];
        __syncthreads();
    }

#pragma unroll
    for (int j = 0; j < EPT; ++j) {
        int i = base + j * 256 + t;
        if (i < e) {
            int d = dst[i];
            unsigned int pk = (unsigned int)src[i] | ((unsigned int)d << 16);   // N < 65536
            int bk = d >> BKT_SH;
            int p  = excl[bk] + atomicAdd(&hist[bk], 1);
            stage[p] = pk;
        }
    }
    __syncthreads();

    int nchunk = min(CHUNK, e - base);
    for (int i = t; i < nchunk; i += 256) {
        unsigned int u = stage[i];
        int b = (int)(u >> 16) >> BKT_SH;
        bpack[gbase[b] + (i - excl[b])] = u;
    }
}

// ---------------- pass B: per-bucket counting sort -> dinv/row_start/csr_src ----------------
__global__ void k_binB(const int* __restrict__ bstart, const unsigned int* __restrict__ bpack,
                       int* __restrict__ row_start, float* __restrict__ dinv,
                       int* __restrict__ csr_src, int n, int e, int nbkt) {
    __shared__ int hist[BKT_N];
    __shared__ int excl[BKT_N];
    __shared__ int wtot[4];
    const int t = threadIdx.x;
    const int b = blockIdx.x;
    const int beg = bstart[b], end = bstart[b + 1];
    const int nodebase = b << BKT_SH;
    const int nloc = min(BKT_N, n - nodebase);

    for (int i = t; i < nloc; i += 256) hist[i] = 0;
    __syncthreads();
    for (int i = beg + t; i < end; i += 256)
        atomicAdd(&hist[(int)(bpack[i] >> 16) - nodebase], 1);
    __syncthreads();

    {
        int idx = t;
        int v = (idx < nloc) ? hist[idx] : 0;
        int inc = v; int lane = t & 63; int wv = t >> 6;
        for (int o = 1; o < 64; o <<= 1) { int u = __shfl_up(inc, o); if (lane >= o) inc += u; }
        if (lane == 63) wtot[wv] = inc;
        __syncthreads();
        int add = 0;
        for (int k = 0; k < wv; ++k) add += wtot[k];
        if (idx < nloc) excl[idx] = add + inc - v;
    }
    __syncthreads();

    for (int i = t; i < nloc; i += 256) {
        row_start[nodebase + i] = beg + excl[i];
        dinv[nodebase + i] = rsqrtf((float)hist[i] + 1.0f);   // +1 self loop
    }
    if (b == nbkt - 1 && t == 0) row_start[n] = e;
    __syncthreads();
    for (int i = t; i < nloc; i += 256) hist[i] = 0;   // reuse as cursors
    __syncthreads();

    for (int i = beg + t; i < end; i += 256) {
        unsigned int u = bpack[i];
        int dl = (int)(u >> 16) - nodebase;
        int p = beg + excl[dl] + atomicAdd(&hist[dl], 1);
        csr_src[p] = (int)(u & 0xFFFFu);
    }
}

// ---------------- GEMM1: h1b = bf16(dinv[row] * (X @ W1))  (N x 64) ----------------
__global__ void k_gemm1(const float* __restrict__ X, const float* __restrict__ W1,
                        const float* __restrict__ dinv, unsigned short* __restrict__ h1b, int n) {
    __shared__ float xt[C_IN][64];
    __shared__ float wl[C_IN * C_HID];
    const int t = threadIdx.x;
    const int row0 = blockIdx.x * 64;

    for (int i = t; i < C_IN * C_HID; i += 256) wl[i] = W1[i];
    {
        int r = t >> 2, q = t & 3;
        int grow = row0 + r;
        for (int j = 0; j < 8; ++j) {
            int k = q * 32 + j * 4;
            float4 v = make_float4(0.f, 0.f, 0.f, 0.f);
            if (grow < n) v = *(const float4*)(X + (size_t)grow * C_IN + k);
            xt[k + 0][r] = v.x; xt[k + 1][r] = v.y; xt[k + 2][r] = v.z; xt[k + 3][r] = v.w;
        }
    }
    __syncthreads();

    const int rg = t >> 4, cg = t & 15;
    const int r0 = rg * 4, c0 = cg * 4;
    float acc[4][4] = {};
#pragma unroll 4
    for (int k = 0; k < C_IN; ++k) {
        float4 a = *(const float4*)&xt[k][r0];
        float4 b = *(const float4*)&wl[k * C_HID + c0];
        acc[0][0] = fmaf(a.x, b.x, acc[0][0]); acc[0][1] = fmaf(a.x, b.y, acc[0][1]);
        acc[0][2] = fmaf(a.x, b.z, acc[0][2]); acc[0][3] = fmaf(a.x, b.w, acc[0][3]);
        acc[1][0] = fmaf(a.y, b.x, acc[1][0]); acc[1][1] = fmaf(a.y, b.y, acc[1][1]);
        acc[1][2] = fmaf(a.y, b.z, acc[1][2]); acc[1][3] = fmaf(a.y, b.w, acc[1][3]);
        acc[2][0] = fmaf(a.z, b.x, acc[2][0]); acc[2][1] = fmaf(a.z, b.y, acc[2][1]);
        acc[2][2] = fmaf(a.z, b.z, acc[2][2]); acc[2][3] = fmaf(a.z, b.w, acc[2][3]);
        acc[3][0] = fmaf(a.w, b.x, acc[3][0]); acc[3][1] = fmaf(a.w, b.y, acc[3][1]);
        acc[3][2] = fmaf(a.w, b.z, acc[3][2]); acc[3][3] = fmaf(a.w, b.w, acc[3][3]);
    }
#pragma unroll
    for (int i = 0; i < 4; ++i) {
        int row = row0 + r0 + i;
        if (row < n) {
            float di = dinv[row];
            ushort4 o;
            o.x = f2bf(di * acc[i][0]); o.y = f2bf(di * acc[i][1]);
            o.z = f2bf(di * acc[i][2]); o.w = f2bf(di * acc[i][3]);
            *(ushort4*)(h1b + (size_t)row * C_HID + c0) = o;
        }
    }
}

// ------- layer-1 aggregate + bias + relu (packed-dword gather), out1 bf16 -------
// 256 threads = 4 waves = 4 nodes per block. NO LDS -> full occupancy.
__global__ void k_agg1(const int* __restrict__ row_start, const int* __restrict__ csr_src,
                       const unsigned short* __restrict__ h1b, const float* __restrict__ dinv,
                       const float* __restrict__ b1, unsigned int* __restrict__ out1d, int n) {
    const int t = threadIdx.x;
    const int wid  = t >> 6;
    const int lane = t & 63;
    const int node = blockIdx.x * 4 + wid;
    if (node >= n) return;

    const int h  = lane >> 5;       // which edge of the pair
    const int c2 = lane & 31;       // dword index within row
    const unsigned int* h1d = (const unsigned int*)h1b;

    int beg = row_start[node], end = row_start[node + 1];
    float alo[4] = {0.f, 0.f, 0.f, 0.f}, ahi[4] = {0.f, 0.f, 0.f, 0.f};
    {   // self term (prescaled by dinv[node]); only half h==0 contributes
        unsigned int u = h1d[(size_t)node * H1DW + c2];
        if (h == 0) {
            alo[0] = __uint_as_float(u << 16);
            ahi[0] = __uint_as_float(u & 0xFFFF0000u);
        }
    }
    for (int j = beg; j < end; j += 64) {
        int sv = (j + lane < end) ? csr_src[j + lane] : 0;
        int m  = min(64, end - j);
        for (int k = 0; k < m; k += 8) {
#pragma unroll
            for (int i = 0; i < 4; ++i) {
                int idx = k + 2 * i + h;                 // <= 63 always
                int s   = __shfl(sv, idx);
                float f = (idx < m) ? 1.f : 0.f;
                unsigned int u = h1d[(size_t)s * H1DW + c2];
                alo[i] = fmaf(f, __uint_as_float(u << 16), alo[i]);
                ahi[i] = fmaf(f, __uint_as_float(u & 0xFFFF0000u), ahi[i]);
            }
        }
    }
    float lo = (alo[0] + alo[1]) + (alo[2] + alo[3]);
    float hi = (ahi[0] + ahi[1]) + (ahi[2] + ahi[3]);
    lo += __shfl_xor(lo, 32);                            // combine halves
    hi += __shfl_xor(hi, 32);

    if (h == 0) {                                        // lanes 0-31: bias+relu -> bf16 pair
        float di = dinv[node];
        float2 bb = *(const float2*)(b1 + 2 * c2);
        float vlo = di * lo + bb.x;
        float vhi = di * hi + bb.y;
        vlo = vlo > 0.f ? vlo : 0.f;
        vhi = vhi > 0.f ? vhi : 0.f;
        out1d[(size_t)node * H1DW + c2] =
            (unsigned int)f2bf(vlo) | ((unsigned int)f2bf(vhi) << 16);
    }
}

// ---------------- GEMM2: h2b = bf16(dinv[row] * (out1 @ W2))  (N x 40) ----------------
// 96-row x 40-col tile; 240 active threads, 4x4 register tile each.
__global__ void k_gemm2(const unsigned int* __restrict__ out1d, const float* __restrict__ W2,
                        const float* __restrict__ dinv, unsigned int* __restrict__ h2d, int n) {
    __shared__ float xt[C_HID][96];        // 24 KB (transposed f32)
    __shared__ float wl[C_HID * C_OUT];    // 10 KB
    const int t = threadIdx.x;
    const int row0 = blockIdx.x * 96;

    for (int i = t; i < C_HID * C_OUT; i += 256) wl[i] = W2[i];
    for (int idx = t; idx < 96 * H1DW; idx += 256) {
        int r = idx >> 5, d = idx & 31;
        int grow = row0 + r;
        unsigned int u = (grow < n) ? out1d[(size_t)grow * H1DW + d] : 0u;
        xt[2 * d][r]     = __uint_as_float(u << 16);
        xt[2 * d + 1][r] = __uint_as_float(u & 0xFFFF0000u);
    }
    __syncthreads();

    if (t >= 240) return;
    const int rg = t / 10, cg = t - rg * 10;   // 24 x 10
    const int r0 = rg * 4, c0 = cg * 4;
    float acc[4][4] = {};
#pragma unroll 4
    for (int k = 0; k < C_HID; ++k) {
        float4 a = *(const float4*)&xt[k][r0];
        float4 b = *(const float4*)&wl[k * C_OUT + c0];
        acc[0][0] = fmaf(a.x, b.x, acc[0][0]); acc[0][1] = fmaf(a.x, b.y, acc[0][1]);
        acc[0][2] = fmaf(a.x, b.z, acc[0][2]); acc[0][3] = fmaf(a.x, b.w, acc[0][3]);
        acc[1][0] = fmaf(a.y, b.x, acc[1][0]); acc[1][1] = fmaf(a.y, b.y, acc[1][1]);
        acc[1][2] = fmaf(a.y, b.z, acc[1][2]); acc[1][3] = fmaf(a.y, b.w, acc[1][3]);
        acc[2][0] = fmaf(a.z, b.x, acc[2][0]); acc[2][1] = fmaf(a.z, b.y, acc[2][1]);
        acc[2][2] = fmaf(a.z, b.z, acc[2][2]); acc[2][3] = fmaf(a.z, b.w, acc[2][3]);
        acc[3][0] = fmaf(a.w, b.x, acc[3][0]); acc[3][1] = fmaf(a.w, b.y, acc[3][1]);
        acc[3][2] = fmaf(a.w, b.z, acc[3][2]); acc[3][3] = fmaf(a.w, b.w, acc[3][3]);
    }
#pragma unroll
    for (int i = 0; i < 4; ++i) {
        int row = row0 + r0 + i;
        if (row < n) {
            float di = dinv[row];
            // pack 4 cols (c0 even) into 2 bf16-pair dwords
            unsigned int u0 = (unsigned int)f2bf(di * acc[i][0]) | ((unsigned int)f2bf(di * acc[i][1]) << 16);
            unsigned int u1 = (unsigned int)f2bf(di * acc[i][2]) | ((unsigned int)f2bf(di * acc[i][3]) << 16);
            h2d[(size_t)row * H2DW + (c0 >> 1)]     = u0;
            h2d[(size_t)row * H2DW + (c0 >> 1) + 1] = u1;
        }
    }
}

// ------- layer-2 aggregate + bias + log_softmax (packed-dword gather, 3 edges/round) -------
__global__ void k_agg2(const int* __restrict__ row_start, const int* __restrict__ csr_src,
                       const unsigned short* __restrict__ h2b, const float* __restrict__ dinv,
                       const float* __restrict__ b2, float* __restrict__ out, int n) {
    int node = (blockIdx.x * 256 + threadIdx.x) >> 6;
    int lane = threadIdx.x & 63;
    if (node >= n) return;
    const int h3 = lane / 20;
    const int c2 = lane - h3 * 20;
    const unsigned int* h2d = (const unsigned int*)h2b;

    int beg = row_start[node], end = row_start[node + 1];
    float alo[4] = {0.f, 0.f, 0.f, 0.f}, ahi[4] = {0.f, 0.f, 0.f, 0.f};
    if (h3 == 0) {   // self term
        unsigned int u = h2d[(size_t)node * H2DW + c2];
        alo[0] = __uint_as_float(u << 16);
        ahi[0] = __uint_as_float(u & 0xFFFF0000u);
    }
    for (int j = beg; j < end; j += 64) {
        int sv = (j + lane < end) ? csr_src[j + lane] : 0;
        int m = min(64, end - j);
        for (int k = 0; k < m; k += 12) {
#pragma unroll
            for (int i = 0; i < 4; ++i) {
                int idx = k + 3 * i + h3;
                int s = __shfl(sv, idx & 63);
                float f = (idx < m) ? 1.f : 0.f;
                unsigned int u = h2d[(size_t)s * H2DW + c2];
                alo[i] = fmaf(f, __uint_as_float(u << 16), alo[i]);
                ahi[i] = fmaf(f, __uint_as_float(u & 0xFFFF0000u), ahi[i]);
            }
        }
    }
    float lo = (alo[0] + alo[1]) + (alo[2] + alo[3]);
    float hi = (ahi[0] + ahi[1]) + (ahi[2] + ahi[3]);
    float lA = __shfl(lo, c2 + 20), lB = __shfl(lo, c2 + 40);
    float hA = __shfl(hi, c2 + 20), hB = __shfl(hi, c2 + 40);
    lo += lA + lB;
    hi += hA + hB;

    float di = dinv[node];
    float vlo = -INFINITY, vhi = -INFINITY, ex = 0.f;
    if (h3 == 0) {
        float2 bb = *(const float2*)(b2 + 2 * c2);
        vlo = di * lo + bb.x;
        vhi = di * hi + bb.y;
    }
    float mx = fmaxf(vlo, vhi);
    for (int off = 16; off; off >>= 1) mx = fmaxf(mx, __shfl_xor(mx, off));
    if (h3 == 0) ex = expf(vlo - mx) + expf(vhi - mx);
    float ss = ex;
    for (int off = 16; off; off >>= 1) ss += __shfl_xor(ss, off);
    float lse = mx + logf(ss);
    if (h3 == 0)
        *(float2*)(out + (size_t)node * C_OUT + 2 * c2) = make_float2(vlo - lse, vhi - lse);
}

extern "C" void kernel_launch(void* const* d_in, const int* in_sizes, int n_in,
                              void* d_out, int out_size, void* d_ws, size_t ws_size,
                              hipStream_t stream) {
    const float* X   = (const float*)d_in[0];
    const int*   src = (const int*)d_in[1];
    const int*   dst = (const int*)d_in[2];
    const float* W1  = (const float*)d_in[3];
    const float* b1  = (const float*)d_in[4];
    const float* W2  = (const float*)d_in[5];
    const float* b2  = (const float*)d_in[6];
    float* out = (float*)d_out;

    const int N = in_sizes[0] / C_IN;
    const int E = in_sizes[1];
    const int NBKT = (N + BKT_N - 1) >> BKT_SH;
    const int nchunks = (E + CHUNK - 1) / CHUNK;

    // workspace layout
    char* ws = (char*)d_ws;
    size_t off = 0;
    auto take = [&](size_t bytes) { char* p = ws + off; off = (off + bytes + 255) & ~(size_t)255; return p; };
    int*   hist2d    = (int*)  take((size_t)nchunks * NBKT * 4);
    int*   base2d    = (int*)  take((size_t)nchunks * NBKT * 4);
    int*   tot       = (int*)  take(512 * 4);
    int*   bstart    = (int*)  take(512 * 4);
    unsigned int* bpack = (unsigned int*)take((size_t)E * 4);
    int*   csr_src   = (int*)  take((size_t)E * 4);
    int*   row_start = (int*)  take((size_t)(N + 1) * 4);
    float* dinv      = (float*)take((size_t)N * 4);
    unsigned short* h1b  = (unsigned short*)take((size_t)N * C_HID * 2);
    unsigned int*   out1 = (unsigned int*)  take((size_t)N * H1DW * 4);
    unsigned int*   h2d  = (unsigned int*)  take((size_t)N * H2DW * 4);

    k_hist    <<<nchunks, 256, 0, stream>>>(dst, hist2d, E, NBKT);
    k_bktscan <<<NBKT, 256, 0, stream>>>(hist2d, base2d, tot, nchunks, NBKT);
    k_scan_bkt<<<1, 256, 0, stream>>>(tot, bstart, NBKT, E);
    k_binA    <<<nchunks, 256, 0, stream>>>(src, dst, bstart, hist2d, base2d, bpack, E, NBKT);
    k_binB    <<<NBKT, 256, 0, stream>>>(bstart, bpack, row_start, dinv, csr_src, N, E, NBKT);

    k_gemm1   <<<(N + 63) / 64, 256, 0, stream>>>(X, W1, dinv, h1b, N);
    k_agg1    <<<(N + 3) / 4, 256, 0, stream>>>(row_start, csr_src, h1b, dinv, b1, out1, N);
    k_gemm2   <<<(N + 95) / 96, 256, 0, stream>>>(out1, W2, dinv, h2d, N);
    k_agg2    <<<((size_t)N * 64 + 255) / 256, 256, 0, stream>>>(row_start, csr_src,
                                                                 (const unsigned short*)h2d, dinv, b2, out, N);
}